// Round 5
// baseline (32.654 us; speedup 1.0000x reference)
//
#include <hip/hip_runtime.h>
#include <math.h>

// CMaxPool4d v4b: input (8, 2, 32, 16, 16, 16, 16) fp32.
// r = in[:,0], i = in[:,1]; mod = sqrt_rn(r*r+i*i); 2x2x2x2 window argmax
// (np.argmax first-occurrence) over last 4 dims; emit (r,i) at argmax.
// Output (8, 2, 32, 8, 8, 8, 8).
//
// v4b = v1 compute (bit-exact: contract-off, __fsqrt_rn, ascending scan order
// + strict >) with NONTEMPORAL loads/stores via clang ext_vector types
// (HIP float4 is a struct -> builtin rejects it; ext_vector_type works).
// Zero-reuse stream: `nt` (L2 evict-first) on 134 MB read + 8 MB write.
//
// History: v2 (wave-contiguous 1KB loads) neutral; v3 (squared-modulus compare
// + rare-tie branch) -14%. VALU ~8% busy; limiter is the read stream.

typedef float vfloat4 __attribute__((ext_vector_type(4)));
typedef float vfloat2 __attribute__((ext_vector_type(2)));

__global__ __launch_bounds__(256) void cmaxpool4d_v4(
    const float* __restrict__ in, float* __restrict__ out)
{
#pragma clang fp contract(off)   // bit-match numpy: no FMA fusion of r*r + i*i
    const int t = blockIdx.x * 256 + threadIdx.x;

    const int t4 = t & 3;          // o4 = 2*t4, 2*t4+1  (d4 base = 4*t4)
    const int o3 = (t >> 2) & 7;
    const int o2 = (t >> 5) & 7;
    const int o1 = (t >> 8) & 7;
    const int c  = (t >> 11) & 31;
    const int b  = t >> 16;

    const size_t planeElems = 65536;                 // 16^4
    const float* __restrict__ pr = in + (((size_t)b * 2 + 0) * 32 + c) * planeElems;
    const float* __restrict__ pi = in + (((size_t)b * 2 + 1) * 32 + c) * planeElems;

    float bm0 = -1.0f, br0 = 0.0f, bi0 = 0.0f;   // window 0 (o4 = 2*t4)
    float bm1 = -1.0f, br1 = 0.0f, bi1 = 0.0f;   // window 1 (o4 = 2*t4+1)

    const int d4b = 4 * t4;

    // w = k1*8 + k2*4 + k3*2 + k4 strictly ascending -> strict > keeps the
    // first occurrence of the max, matching np.argmax.
#pragma unroll
    for (int k1 = 0; k1 < 2; ++k1) {
        const int d1 = 2 * o1 + k1;
#pragma unroll
        for (int k2 = 0; k2 < 2; ++k2) {
            const int d2 = 2 * o2 + k2;
#pragma unroll
            for (int k3 = 0; k3 < 2; ++k3) {
                const int d3 = 2 * o3 + k3;
                const size_t off = (((size_t)d1 * 16 + d2) * 16 + d3) * 16 + d4b;
                const vfloat4 r4 = __builtin_nontemporal_load(
                    reinterpret_cast<const vfloat4*>(pr + off));
                const vfloat4 i4 = __builtin_nontemporal_load(
                    reinterpret_cast<const vfloat4*>(pi + off));

                float rr, ii, s, m;
                // k4 = 0, 1 -> window 0
                rr = r4.x * r4.x; ii = i4.x * i4.x; s = rr + ii; m = __fsqrt_rn(s);
                if (m > bm0) { bm0 = m; br0 = r4.x; bi0 = i4.x; }
                rr = r4.y * r4.y; ii = i4.y * i4.y; s = rr + ii; m = __fsqrt_rn(s);
                if (m > bm0) { bm0 = m; br0 = r4.y; bi0 = i4.y; }
                // -> window 1
                rr = r4.z * r4.z; ii = i4.z * i4.z; s = rr + ii; m = __fsqrt_rn(s);
                if (m > bm1) { bm1 = m; br1 = r4.z; bi1 = i4.z; }
                rr = r4.w * r4.w; ii = i4.w * i4.w; s = rr + ii; m = __fsqrt_rn(s);
                if (m > bm1) { bm1 = m; br1 = r4.w; bi1 = i4.w; }
            }
        }
    }

    // output: (((b*2+ch)*32 + c)*4096) + o1*512 + o2*64 + o3*8 + o4
    const size_t outPlane = 4096;                     // 8^4
    const size_t oOff = (size_t)o1 * 512 + (size_t)o2 * 64 + (size_t)o3 * 8 + 2 * t4;
    float* __restrict__ qr = out + (((size_t)b * 2 + 0) * 32 + c) * outPlane + oOff;
    float* __restrict__ qi = out + (((size_t)b * 2 + 1) * 32 + c) * outPlane + oOff;

    vfloat2 vr; vr.x = br0; vr.y = br1;
    vfloat2 vi; vi.x = bi0; vi.y = bi1;
    __builtin_nontemporal_store(vr, reinterpret_cast<vfloat2*>(qr));
    __builtin_nontemporal_store(vi, reinterpret_cast<vfloat2*>(qi));
}

extern "C" void kernel_launch(void* const* d_in, const int* in_sizes, int n_in,
                              void* d_out, int out_size, void* d_ws, size_t ws_size,
                              hipStream_t stream) {
    (void)in_sizes; (void)n_in; (void)d_ws; (void)ws_size; (void)out_size;
    const float* in = (const float*)d_in[0];
    float* out = (float*)d_out;

    const int nThreads = 8 * 32 * 8 * 8 * 8 * 4;     // 524288
    const int block = 256;
    const int grid = nThreads / block;               // 2048
    cmaxpool4d_v4<<<grid, block, 0, stream>>>(in, out);
}

// Round 6
// 30.320 us; speedup vs baseline: 1.0770x; 1.0770x over previous
//
#include <hip/hip_runtime.h>
#include <math.h>

// CMaxPool4d v5: input (8, 2, 32, 16, 16, 16, 16) fp32.
// mod = sqrt_rn(r*r+i*i); 2x2x2x2 window argmax over last 4 dims (np.argmax
// first-occurrence); emit (r,i) at argmax -> (8, 2, 32, 8, 8, 8, 8).
//
// v5 = v2 layout (wave-contiguous 1 KiB loads: lane L covers d3=L>>2,
// d4-quad=L&3, so each 128B line is touched by EXACTLY ONE instruction once)
// + nontemporal loads. v4's nt regression was a confound: v1's layout touches
// each line with two instructions (k3 pair), so nt caused refetch. v2's
// single-touch pattern is the clean test of the L2-allocation-overhead theory.
// Stores stay cached (8 MB only; one variable at a time).
//
// History: v1 27.7 | v2 27.3 (contig loads neutral) | v3 31.1 (sq-compare
// branch hurt) | v4 32.7 (nt on reuse-pattern hurt: line refetch).

typedef float vfloat4 __attribute__((ext_vector_type(4)));

__global__ __launch_bounds__(256) void cmaxpool4d_v5(
    const float* __restrict__ in, float* __restrict__ out)
{
#pragma clang fp contract(off)   // bit-match numpy: no FMA fusion of r*r + i*i
    const int tid = blockIdx.x * 256 + threadIdx.x;
    const int W = tid >> 6;            // wave id: 8*32*8*4 = 8192 waves
    const int L = threadIdx.x & 63;

    const int o2p = W & 3;             // o2 pair
    const int o1  = (W >> 2) & 7;
    const int c   = (W >> 5) & 31;
    const int b   = W >> 10;

    const int qd4 = L & 3;             // d4 = 4*qd4 .. 4*qd4+3
    const int d3  = L >> 2;            // 0..15
    const int k3  = d3 & 1;            // window parity along d3
    const int o3  = L >> 3;            // d3 >> 1

    const size_t plane = 65536;        // 16^4
    const float* __restrict__ pr = in + (((size_t)b * 2 + 0) * 32 + c) * plane;
    const float* __restrict__ pi = in + (((size_t)b * 2 + 1) * 32 + c) * plane;
    const int laneOff = 4 * L;         // floats: d3*16 + 4*qd4 == 4*L

    for (int jo2 = 0; jo2 < 2; ++jo2) {
        const int o2 = 2 * o2p + jo2;

        // window 0: o4 = 2*qd4 ; window 1: o4 = 2*qd4+1
        float bm0 = -1.0f, br0 = 0.0f, bi0 = 0.0f;
        float bm1 = -1.0f, br1 = 0.0f, bi1 = 0.0f;
        int bw0 = 0, bw1 = 0;          // window index of current best

        // in-thread scan: w = k1*8 + k2*4 + k3*2 + k4 ascending (k3 fixed per
        // lane) -> strict > keeps earliest max.
#pragma unroll
        for (int k1 = 0; k1 < 2; ++k1) {
            const int d1 = 2 * o1 + k1;
#pragma unroll
            for (int k2 = 0; k2 < 2; ++k2) {
                const int d2 = 2 * o2 + k2;
                const size_t off = (size_t)(d1 * 16 + d2) * 256 + laneOff;
                const vfloat4 r4 = __builtin_nontemporal_load(
                    reinterpret_cast<const vfloat4*>(pr + off));
                const vfloat4 i4 = __builtin_nontemporal_load(
                    reinterpret_cast<const vfloat4*>(pi + off));
                const int wb = k1 * 8 + k2 * 4 + k3 * 2;

                float rr, ii, s, m;
                rr = r4.x * r4.x; ii = i4.x * i4.x; s = rr + ii; m = __fsqrt_rn(s);
                if (m > bm0) { bm0 = m; br0 = r4.x; bi0 = i4.x; bw0 = wb; }
                rr = r4.y * r4.y; ii = i4.y * i4.y; s = rr + ii; m = __fsqrt_rn(s);
                if (m > bm0) { bm0 = m; br0 = r4.y; bi0 = i4.y; bw0 = wb + 1; }
                rr = r4.z * r4.z; ii = i4.z * i4.z; s = rr + ii; m = __fsqrt_rn(s);
                if (m > bm1) { bm1 = m; br1 = r4.z; bi1 = i4.z; bw1 = wb; }
                rr = r4.w * r4.w; ii = i4.w * i4.w; s = rr + ii; m = __fsqrt_rn(s);
                if (m > bm1) { bm1 = m; br1 = r4.w; bi1 = i4.w; bw1 = wb + 1; }
            }
        }

        // cross-lane merge over k3 (partner lane L^4). Value-tie -> smaller w
        // wins (np.argmax first-occurrence). Symmetric: both lanes agree.
        {
            const float mo = __shfl_xor(bm0, 4);
            const int   wo = __shfl_xor(bw0, 4);
            const float ro = __shfl_xor(br0, 4);
            const float io = __shfl_xor(bi0, 4);
            if (mo > bm0 || (mo == bm0 && wo < bw0)) {
                bm0 = mo; br0 = ro; bi0 = io; bw0 = wo;
            }
        }
        {
            const float mo = __shfl_xor(bm1, 4);
            const int   wo = __shfl_xor(bw1, 4);
            const float ro = __shfl_xor(br1, 4);
            const float io = __shfl_xor(bi1, 4);
            if (mo > bm1 || (mo == bm1 && wo < bw1)) {
                bm1 = mo; br1 = ro; bi1 = io; bw1 = wo;
            }
        }

        // even-d3 lanes store r outputs, odd-d3 lanes store i outputs
        const int ch = k3;
        float* __restrict__ q = out + (((size_t)b * 2 + ch) * 32 + c) * 4096
                              + (size_t)o1 * 512 + (size_t)o2 * 64
                              + (size_t)o3 * 8 + 2 * qd4;
        const float2 v = ch ? make_float2(bi0, bi1) : make_float2(br0, br1);
        *reinterpret_cast<float2*>(q) = v;
    }
}

extern "C" void kernel_launch(void* const* d_in, const int* in_sizes, int n_in,
                              void* d_out, int out_size, void* d_ws, size_t ws_size,
                              hipStream_t stream) {
    (void)in_sizes; (void)n_in; (void)d_ws; (void)ws_size; (void)out_size;
    const float* in = (const float*)d_in[0];
    float* out = (float*)d_out;

    const int nThreads = 8192 * 64;                  // 8192 waves
    const int block = 256;
    const int grid = nThreads / block;               // 2048
    cmaxpool4d_v5<<<grid, block, 0, stream>>>(in, out);
}

// Round 7
// 27.226 us; speedup vs baseline: 1.1994x; 1.1136x over previous
//
#include <hip/hip_runtime.h>
#include <math.h>

// CMaxPool4d FINAL (= v2, best measured: 27.35 us, absmax 0.0).
// input (8, 2, 32, 16, 16, 16, 16) fp32; r = in[:,0], i = in[:,1];
// mod = sqrt_rn(r*r+i*i); 2x2x2x2 window argmax over last 4 dims with
// np.argmax first-occurrence tie semantics; emit (r,i) at argmax.
// Output (8, 2, 32, 8, 8, 8, 8).
//
// Layout: one WAVE owns one (b, c, o1, o2-pair). Lane L covers the full
// (d3 = L>>2, d4-quad = L&3) slice, so each float4 load is a perfectly
// contiguous 1 KiB wave access. k3 (d3-window) pooling is cross-lane via
// __shfl_xor(.,4), carrying the window index w to break fp-equal modulus
// ties exactly like np.argmax (sqrt compresses ~2ulp -> real ties exist).
// Bit-exactness requirements: contract(off) (no FMA in r*r+i*i), __fsqrt_rn,
// ascending in-thread scan order + strict >.
//
// Ledger: v1 27.7 | v2 27.3 | v3 31.1 (sq-compare branch) | v4 32.7 (nt on
// line-reuse layout) | v5 30.3 (nt on single-touch layout). nt falsified;
// VALU ~8%; read stream at ~4.9 TB/s = this part's read-stream ceiling
// (cf. fills 7.1 TB/s write-only, float4 copy 6.29 TB/s aggregate).

typedef float vfloat4 __attribute__((ext_vector_type(4)));

__global__ __launch_bounds__(256) void cmaxpool4d_final(
    const float* __restrict__ in, float* __restrict__ out)
{
#pragma clang fp contract(off)
    const int tid = blockIdx.x * 256 + threadIdx.x;
    const int W = tid >> 6;            // wave id: 8*32*8*4 = 8192 waves
    const int L = threadIdx.x & 63;

    const int o2p = W & 3;             // o2 pair
    const int o1  = (W >> 2) & 7;
    const int c   = (W >> 5) & 31;
    const int b   = W >> 10;

    const int qd4 = L & 3;             // d4 = 4*qd4 .. 4*qd4+3
    const int d3  = L >> 2;            // 0..15
    const int k3  = d3 & 1;            // window parity along d3
    const int o3  = L >> 3;            // d3 >> 1

    const size_t plane = 65536;        // 16^4
    const float* __restrict__ pr = in + (((size_t)b * 2 + 0) * 32 + c) * plane;
    const float* __restrict__ pi = in + (((size_t)b * 2 + 1) * 32 + c) * plane;
    const int laneOff = 4 * L;         // floats: d3*16 + 4*qd4 == 4*L

    for (int jo2 = 0; jo2 < 2; ++jo2) {
        const int o2 = 2 * o2p + jo2;

        float bm0 = -1.0f, br0 = 0.0f, bi0 = 0.0f;   // window 0 (o4 = 2*qd4)
        float bm1 = -1.0f, br1 = 0.0f, bi1 = 0.0f;   // window 1 (o4 = 2*qd4+1)
        int bw0 = 0, bw1 = 0;          // window index of current best

#pragma unroll
        for (int k1 = 0; k1 < 2; ++k1) {
            const int d1 = 2 * o1 + k1;
#pragma unroll
            for (int k2 = 0; k2 < 2; ++k2) {
                const int d2 = 2 * o2 + k2;
                const size_t off = (size_t)(d1 * 16 + d2) * 256 + laneOff;
                const vfloat4 r4 = *reinterpret_cast<const vfloat4*>(pr + off);
                const vfloat4 i4 = *reinterpret_cast<const vfloat4*>(pi + off);
                const int wb = k1 * 8 + k2 * 4 + k3 * 2;

                float rr, ii, s, m;
                rr = r4.x * r4.x; ii = i4.x * i4.x; s = rr + ii; m = __fsqrt_rn(s);
                if (m > bm0) { bm0 = m; br0 = r4.x; bi0 = i4.x; bw0 = wb; }
                rr = r4.y * r4.y; ii = i4.y * i4.y; s = rr + ii; m = __fsqrt_rn(s);
                if (m > bm0) { bm0 = m; br0 = r4.y; bi0 = i4.y; bw0 = wb + 1; }
                rr = r4.z * r4.z; ii = i4.z * i4.z; s = rr + ii; m = __fsqrt_rn(s);
                if (m > bm1) { bm1 = m; br1 = r4.z; bi1 = i4.z; bw1 = wb; }
                rr = r4.w * r4.w; ii = i4.w * i4.w; s = rr + ii; m = __fsqrt_rn(s);
                if (m > bm1) { bm1 = m; br1 = r4.w; bi1 = i4.w; bw1 = wb + 1; }
            }
        }

        // cross-lane merge over k3 (partner lane L^4); value-tie -> smaller w.
        {
            const float mo = __shfl_xor(bm0, 4);
            const int   wo = __shfl_xor(bw0, 4);
            const float ro = __shfl_xor(br0, 4);
            const float io = __shfl_xor(bi0, 4);
            if (mo > bm0 || (mo == bm0 && wo < bw0)) {
                bm0 = mo; br0 = ro; bi0 = io; bw0 = wo;
            }
        }
        {
            const float mo = __shfl_xor(bm1, 4);
            const int   wo = __shfl_xor(bw1, 4);
            const float ro = __shfl_xor(br1, 4);
            const float io = __shfl_xor(bi1, 4);
            if (mo > bm1 || (mo == bm1 && wo < bw1)) {
                bm1 = mo; br1 = ro; bi1 = io; bw1 = wo;
            }
        }

        // even-d3 lanes store r outputs, odd-d3 lanes store i outputs
        const int ch = k3;
        float* __restrict__ q = out + (((size_t)b * 2 + ch) * 32 + c) * 4096
                              + (size_t)o1 * 512 + (size_t)o2 * 64
                              + (size_t)o3 * 8 + 2 * qd4;
        const float2 v = ch ? make_float2(bi0, bi1) : make_float2(br0, br1);
        *reinterpret_cast<float2*>(q) = v;
    }
}

extern "C" void kernel_launch(void* const* d_in, const int* in_sizes, int n_in,
                              void* d_out, int out_size, void* d_ws, size_t ws_size,
                              hipStream_t stream) {
    (void)in_sizes; (void)n_in; (void)d_ws; (void)ws_size; (void)out_size;
    const float* in = (const float*)d_in[0];
    float* out = (float*)d_out;

    const int nThreads = 8192 * 64;                  // 8192 waves
    const int block = 256;
    const int grid = nThreads / block;               // 2048
    cmaxpool4d_final<<<grid, block, 0, stream>>>(in, out);
}